// Round 3
// baseline (349.576 us; speedup 1.0000x reference)
//
#include <hip/hip_runtime.h>
#include <hip/hip_bf16.h>
#include <stdint.h>
#include <math.h>

typedef __attribute__((ext_vector_type(8))) short bf16x8;
typedef __attribute__((ext_vector_type(4))) float f32x4;

#define D_K 256
#define JCHUNK 1024

__device__ __forceinline__ unsigned short f2bf(float f) {
    unsigned u = __float_as_uint(f);
    u += 0x7fffu + ((u >> 16) & 1u);   // round-to-nearest-even
    return (unsigned short)(u >> 16);
}

// ---------------- Kernel 1: row-normalize z -> bf16, and zero the partials ----------------
__global__ void normalize_k(const float* __restrict__ z,
                            unsigned short* __restrict__ zn,
                            float* __restrict__ part, int N) {
    int gid  = blockIdx.x * blockDim.x + threadIdx.x;
    if (gid < 5 * N) part[gid] = 0.f;      // zero partials (ordered before fused_k on stream)
    int gw   = gid >> 6;                   // one wave per row
    int lane = threadIdx.x & 63;
    if (gw >= N) return;
    float4 v = reinterpret_cast<const float4*>(z + (size_t)gw * D_K)[lane];
    float ss = v.x * v.x + v.y * v.y + v.z * v.z + v.w * v.w;
#pragma unroll
    for (int m = 32; m; m >>= 1) ss += __shfl_xor(ss, m);
    float sc = 1.0f / fmaxf(sqrtf(ss), 1e-8f);
    ushort4 o;
    o.x = f2bf(v.x * sc); o.y = f2bf(v.y * sc);
    o.z = f2bf(v.z * sc); o.w = f2bf(v.w * sc);
    reinterpret_cast<ushort4*>(zn + (size_t)gw * D_K)[lane] = o;
}

// ---------------- Kernel 2: fused sim-GEMM + row reductions (no LDS, no barriers) ------
// Swapped operand roles: streamed j-rows are the MFMA A operand (output ROWS = j),
// register-held i-rows are the B operand (output COLS = i = lane&15). Each lane then
// owns 4 consecutive j columns per fragment register -> f32x4 adj/tsim loads.
// part layout: [0,N) den | [N,2N) S1 | [2N,3N) A | [3N,4N) T1 | [4N,5N) T
__global__ __launch_bounds__(256, 4) void fused_k(
    const unsigned short* __restrict__ zn,
    const float* __restrict__ adj,
    const float* __restrict__ tsim,
    float* __restrict__ part, int N) {
    const float INV_T = 1.0f / 0.07f;
    const int NIB = N >> 6;                 // 128 i-blocks of 64 rows
    int ib  = blockIdx.x % NIB;
    int jc  = blockIdx.x / NIB;
    int tid = threadIdx.x;
    int wid = tid >> 6, lane = tid & 63;
    int l15 = lane & 15, lhi = lane >> 4;
    int gi  = ib * 64 + wid * 16 + l15;     // this lane's i-row (output col)
    int jbase = jc * JCHUNK;

    // B-operand fragments: zn row gi, held in registers for the whole sweep
    bf16x8 bfr[8];
    {
        const bf16x8* bp = reinterpret_cast<const bf16x8*>(zn + (size_t)gi * D_K) + lhi;
#pragma unroll
        for (int ks = 0; ks < 8; ++ks) bfr[ks] = bp[ks * 4];
    }

    float accden = 0.f, accs1 = 0.f, acca = 0.f, acct1 = 0.f, acctt = 0.f;

    const float* abase = adj  + (size_t)gi * N + jbase + lhi * 4;
    const float* tbase = tsim + (size_t)gi * N + jbase + lhi * 4;

    for (int jt = 0; jt < JCHUNK / 64; ++jt) {
        int j0 = jbase + jt * 64;

        // ---- issue adj/tsim f32x4 loads early (consumed after MFMA) ----
        f32x4 av[4], tv[4];
#pragma unroll
        for (int t = 0; t < 4; ++t) {
            av[t] = __builtin_nontemporal_load(
                reinterpret_cast<const f32x4*>(abase + t * 16));
            tv[t] = __builtin_nontemporal_load(
                reinterpret_cast<const f32x4*>(tbase + t * 16));
        }

        // ---- A fragments straight from L2-resident zn + MFMA ----
        const bf16x8* ar[4];
#pragma unroll
        for (int t = 0; t < 4; ++t)
            ar[t] = reinterpret_cast<const bf16x8*>(
                        zn + (size_t)(j0 + t * 16 + l15) * D_K) + lhi;

        f32x4 acc[4];
#pragma unroll
        for (int t = 0; t < 4; ++t) acc[t] = (f32x4){0.f, 0.f, 0.f, 0.f};
#pragma unroll
        for (int ks = 0; ks < 8; ++ks) {
            bf16x8 aj[4];
#pragma unroll
            for (int t = 0; t < 4; ++t) aj[t] = ar[t][ks * 4];
#pragma unroll
            for (int t = 0; t < 4; ++t)
                acc[t] = __builtin_amdgcn_mfma_f32_16x16x32_bf16(aj[t], bfr[ks], acc[t], 0, 0, 0);
        }

        // ---- epilogue: exp, mask diag, accumulate 5 row-scalars ----
#pragma unroll
        for (int t = 0; t < 4; ++t) {
            int gj0 = j0 + t * 16 + lhi * 4;
#pragma unroll
            for (int r = 0; r < 4; ++r) {
                float sim = acc[t][r] * INV_T;
                float e   = (gi == gj0 + r) ? 0.f : __expf(sim);
                float a   = av[t][r];
                float w   = tv[t][r];
                accden += e;
                accs1 = fmaf(a, sim, accs1);  acca  += a;
                acct1 = fmaf(w, sim, acct1);  acctt += w;
            }
        }
        abase += 64; tbase += 64;
    }

    // lanes lhi=0..3 share the same gi: reduce, then one atomic per row per counter
    accden += __shfl_xor(accden, 16); accden += __shfl_xor(accden, 32);
    accs1  += __shfl_xor(accs1, 16);  accs1  += __shfl_xor(accs1, 32);
    acca   += __shfl_xor(acca, 16);   acca   += __shfl_xor(acca, 32);
    acct1  += __shfl_xor(acct1, 16);  acct1  += __shfl_xor(acct1, 32);
    acctt  += __shfl_xor(acctt, 16);  acctt  += __shfl_xor(acctt, 32);
    if (lhi == 0) {
        atomicAdd(part + gi, accden);
        atomicAdd(part + (size_t)N + gi, accs1);
        atomicAdd(part + (size_t)2 * N + gi, acca);
        atomicAdd(part + (size_t)3 * N + gi, acct1);
        atomicAdd(part + (size_t)4 * N + gi, acctt);
    }
}

// ---------------- Kernel 3: finalize scalar ----------------
__global__ void finalize_k(const float* __restrict__ part, float* __restrict__ out, int N) {
    const float* den = part;
    const float* s1  = part + (size_t)N;
    const float* aa  = part + (size_t)2 * N;
    const float* t1  = part + (size_t)3 * N;
    const float* tt  = part + (size_t)4 * N;
    float acc = 0.f;
    for (int i = threadIdx.x; i < N; i += blockDim.x) {
        float ld = logf(den[i] + 1e-8f);
        acc += -(s1[i] - ld * aa[i]) / (aa[i] + 1e-8f)
               - (t1[i] - ld * tt[i]) / (tt[i] + 1e-8f);
    }
#pragma unroll
    for (int m = 32; m; m >>= 1) acc += __shfl_xor(acc, m);
    __shared__ float red[16];
    if ((threadIdx.x & 63) == 0) red[threadIdx.x >> 6] = acc;
    __syncthreads();
    if (threadIdx.x == 0) {
        float tot = 0.f;
        int nw = blockDim.x >> 6;
        for (int w = 0; w < nw; ++w) tot += red[w];
        out[0] = tot / (float)N;
    }
}

extern "C" void kernel_launch(void* const* d_in, const int* in_sizes, int n_in,
                              void* d_out, int out_size, void* d_ws, size_t ws_size,
                              hipStream_t stream) {
    const float* z    = (const float*)d_in[0];
    const float* adj  = (const float*)d_in[1];
    const float* tsim = (const float*)d_in[2];

    int N = (int)(sqrt((double)in_sizes[1]) + 0.5);  // 8192

    unsigned short* zn = (unsigned short*)d_ws;                   // N*256 bf16 = 4 MB
    float* part = (float*)((char*)d_ws + (size_t)N * D_K * 2);    // 5*N f32

    normalize_k<<<N / 4, 256, 0, stream>>>(z, zn, part, N);

    int nblocks = (N >> 6) * (N / JCHUNK);  // 128 * 8 = 1024
    fused_k<<<nblocks, 256, 0, stream>>>(zn, adj, tsim, part, N);

    finalize_k<<<1, 1024, 0, stream>>>(part, (float*)d_out, N);
}

// Round 4
// 195.478 us; speedup vs baseline: 1.7883x; 1.7883x over previous
//
#include <hip/hip_runtime.h>
#include <hip/hip_bf16.h>
#include <stdint.h>
#include <math.h>

typedef __attribute__((ext_vector_type(8))) short bf16x8;
typedef __attribute__((ext_vector_type(4))) float f32x4;

#define D_K 256
#define JCHUNK 1024
#define BN 64
#define NJT (JCHUNK / BN)   // 16

__device__ __forceinline__ unsigned short f2bf(float f) {
    unsigned u = __float_as_uint(f);
    u += 0x7fffu + ((u >> 16) & 1u);   // round-to-nearest-even
    return (unsigned short)(u >> 16);
}

__device__ __forceinline__ void gload_lds16(const void* g, void* l) {
    __builtin_amdgcn_global_load_lds(
        (const __attribute__((address_space(1))) void*)g,
        (__attribute__((address_space(3))) void*)l,
        16, 0, 0);
}

// Stage one 64x256 bf16 zn tile (rows j0..j0+64) into LDS, XOR-swizzled via
// pre-swizzled global source (LDS dest stays linear per gload_lds contract).
// LDS[r][c] = zn[j0+r][c ^ ((r&7)<<4)]  (c in bytes, 512B rows)
__device__ __forceinline__ void stage_tile(char* dst_base, const unsigned short* zn,
                                           int j0, int wid, int lane) {
#pragma unroll
    for (int it = 0; it < 8; ++it) {
        int li = (it * 256 + wid * 64 + lane) * 16;   // linear LDS byte this lane fills
        int r  = li >> 9;
        int c  = li & 511;
        const char* src = reinterpret_cast<const char*>(zn) +
                          ((size_t)(j0 + r) << 9) + (size_t)(c ^ ((r & 7) << 4));
        gload_lds16(src, dst_base + it * 4096 + wid * 1024);  // wave-uniform dest base
    }
}

// ---------------- Kernel 1: row-normalize z -> bf16, and zero the partials ----------------
__global__ void normalize_k(const float* __restrict__ z,
                            unsigned short* __restrict__ zn,
                            float* __restrict__ part, int N) {
    int gid  = blockIdx.x * blockDim.x + threadIdx.x;
    if (gid < 5 * N) part[gid] = 0.f;      // zero partials (stream-ordered before fused_k)
    int gw   = gid >> 6;                   // one wave per row
    int lane = threadIdx.x & 63;
    if (gw >= N) return;
    float4 v = reinterpret_cast<const float4*>(z + (size_t)gw * D_K)[lane];
    float ss = v.x * v.x + v.y * v.y + v.z * v.z + v.w * v.w;
#pragma unroll
    for (int m = 32; m; m >>= 1) ss += __shfl_xor(ss, m);
    float sc = 1.0f / fmaxf(sqrtf(ss), 1e-8f);
    ushort4 o;
    o.x = f2bf(v.x * sc); o.y = f2bf(v.y * sc);
    o.z = f2bf(v.z * sc); o.w = f2bf(v.w * sc);
    reinterpret_cast<ushort4*>(zn + (size_t)gw * D_K)[lane] = o;
}

// ---------------- Kernel 2: fused sim-GEMM + row reductions ----------------
// Swapped operands: LDS-staged j-rows are the MFMA A operand (output rows = j),
// register-held i-row is the B operand (output cols = i = lane&15). Each lane owns
// 4 consecutive j per fragment reg -> f32x4 adj/tsim loads (64B/4-lane group).
// Double-buffered LDS: stage jt+1 + issue adj/tsim at top, MFMA from pre-staged
// buffer, epilogue consumes HBM loads after MFMA; one barrier per tile.
// part layout: [0,N) den | [N,2N) S1 | [2N,3N) A | [3N,4N) T1 | [4N,5N) T
__global__ __launch_bounds__(256, 2) void fused_k(
    const unsigned short* __restrict__ zn,
    const float* __restrict__ adj,
    const float* __restrict__ tsim,
    float* __restrict__ part, int N) {
    __shared__ alignas(128) char Bt[2][BN * 512];   // 2 x 32 KB

    const float INV_T = 1.0f / 0.07f;
    const int NIB = N >> 6;                 // 128 i-blocks of 64 rows
    int ib  = blockIdx.x % NIB;
    int jc  = blockIdx.x / NIB;
    int tid = threadIdx.x;
    int wid = tid >> 6, lane = tid & 63;
    int l15 = lane & 15, lhi = lane >> 4;
    int gi  = ib * 64 + wid * 16 + l15;     // this lane's i-row (output col)
    int jbase = jc * JCHUNK;

    // B-operand fragments: zn row gi, registers for the whole sweep (32 VGPRs)
    bf16x8 bfr[8];
    {
        const bf16x8* bp = reinterpret_cast<const bf16x8*>(zn + (size_t)gi * D_K) + lhi;
#pragma unroll
        for (int ks = 0; ks < 8; ++ks) bfr[ks] = bp[ks * 4];
    }

    float accden = 0.f, accs1 = 0.f, acca = 0.f, acct1 = 0.f, acctt = 0.f;

    const float* abase = adj  + (size_t)gi * N + jbase + lhi * 4;
    const float* tbase = tsim + (size_t)gi * N + jbase + lhi * 4;

    // prologue: stage tile 0
    stage_tile(Bt[0], zn, jbase, wid, lane);
    asm volatile("s_waitcnt vmcnt(0)" ::: "memory");
    __syncthreads();

    for (int jt = 0; jt < NJT; ++jt) {
        int cur = jt & 1;
        char* buf = Bt[cur];

        // 1) issue next tile's staging (overlaps with this tile's compute)
        if (jt + 1 < NJT)
            stage_tile(Bt[cur ^ 1], zn, jbase + (jt + 1) * BN, wid, lane);

        // 2) issue adj/tsim vector loads early (consumed after MFMA)
        f32x4 av[4], tv[4];
#pragma unroll
        for (int t = 0; t < 4; ++t) {
            av[t] = __builtin_nontemporal_load(
                reinterpret_cast<const f32x4*>(abase + t * 16));
            tv[t] = __builtin_nontemporal_load(
                reinterpret_cast<const f32x4*>(tbase + t * 16));
        }

        // 3) MFMA from pre-staged LDS (swizzled reads: 2-way max -> free)
        f32x4 acc[4];
#pragma unroll
        for (int t = 0; t < 4; ++t) acc[t] = (f32x4){0.f, 0.f, 0.f, 0.f};
#pragma unroll
        for (int ks = 0; ks < 8; ++ks) {
            bf16x8 aj[4];
#pragma unroll
            for (int t = 0; t < 4; ++t) {
                int brow = t * 16 + l15;
                int boff = (brow << 9) + (((ks << 6) + (lhi << 4)) ^ ((brow & 7) << 4));
                aj[t] = *reinterpret_cast<const bf16x8*>(buf + boff);
            }
#pragma unroll
            for (int t = 0; t < 4; ++t)
                acc[t] = __builtin_amdgcn_mfma_f32_16x16x32_bf16(aj[t], bfr[ks], acc[t], 0, 0, 0);
        }

        // 4) epilogue: exp, mask diag, accumulate 5 row-scalars
        int j0 = jbase + jt * BN;
#pragma unroll
        for (int t = 0; t < 4; ++t) {
            int gj0 = j0 + t * 16 + lhi * 4;
#pragma unroll
            for (int r = 0; r < 4; ++r) {
                float sim = acc[t][r] * INV_T;
                float e   = (gi == gj0 + r) ? 0.f : __expf(sim);
                float a   = av[t][r];
                float w   = tv[t][r];
                accden += e;
                accs1 = fmaf(a, sim, accs1);  acca  += a;
                acct1 = fmaf(w, sim, acct1);  acctt += w;
            }
        }
        abase += BN; tbase += BN;

        // 5) ensure own staging DMA landed (free: epilogue already drained vmcnt),
        //    then barrier so next tile's buffer is globally ready
        asm volatile("s_waitcnt vmcnt(0)" ::: "memory");
        __syncthreads();
    }

    // lanes lhi=0..3 share the same gi: reduce, then one atomic per row per counter
    accden += __shfl_xor(accden, 16); accden += __shfl_xor(accden, 32);
    accs1  += __shfl_xor(accs1, 16);  accs1  += __shfl_xor(accs1, 32);
    acca   += __shfl_xor(acca, 16);   acca   += __shfl_xor(acca, 32);
    acct1  += __shfl_xor(acct1, 16);  acct1  += __shfl_xor(acct1, 32);
    acctt  += __shfl_xor(acctt, 16);  acctt  += __shfl_xor(acctt, 32);
    if (lhi == 0) {
        atomicAdd(part + gi, accden);
        atomicAdd(part + (size_t)N + gi, accs1);
        atomicAdd(part + (size_t)2 * N + gi, acca);
        atomicAdd(part + (size_t)3 * N + gi, acct1);
        atomicAdd(part + (size_t)4 * N + gi, acctt);
    }
}

// ---------------- Kernel 3: finalize scalar ----------------
__global__ void finalize_k(const float* __restrict__ part, float* __restrict__ out, int N) {
    const float* den = part;
    const float* s1  = part + (size_t)N;
    const float* aa  = part + (size_t)2 * N;
    const float* t1  = part + (size_t)3 * N;
    const float* tt  = part + (size_t)4 * N;
    float acc = 0.f;
    for (int i = threadIdx.x; i < N; i += blockDim.x) {
        float ld = logf(den[i] + 1e-8f);
        acc += -(s1[i] - ld * aa[i]) / (aa[i] + 1e-8f)
               - (t1[i] - ld * tt[i]) / (tt[i] + 1e-8f);
    }
#pragma unroll
    for (int m = 32; m; m >>= 1) acc += __shfl_xor(acc, m);
    __shared__ float red[16];
    if ((threadIdx.x & 63) == 0) red[threadIdx.x >> 6] = acc;
    __syncthreads();
    if (threadIdx.x == 0) {
        float tot = 0.f;
        int nw = blockDim.x >> 6;
        for (int w = 0; w < nw; ++w) tot += red[w];
        out[0] = tot / (float)N;
    }
}

extern "C" void kernel_launch(void* const* d_in, const int* in_sizes, int n_in,
                              void* d_out, int out_size, void* d_ws, size_t ws_size,
                              hipStream_t stream) {
    const float* z    = (const float*)d_in[0];
    const float* adj  = (const float*)d_in[1];
    const float* tsim = (const float*)d_in[2];

    int N = (int)(sqrt((double)in_sizes[1]) + 0.5);  // 8192

    unsigned short* zn = (unsigned short*)d_ws;                   // N*256 bf16 = 4 MB
    float* part = (float*)((char*)d_ws + (size_t)N * D_K * 2);    // 5*N f32

    normalize_k<<<N / 4, 256, 0, stream>>>(z, zn, part, N);

    int nblocks = (N >> 6) * (N / JCHUNK);  // 128 * 8 = 1024
    fused_k<<<nblocks, 256, 0, stream>>>(zn, adj, tsim, part, N);

    finalize_k<<<1, 1024, 0, stream>>>(part, (float*)d_out, N);
}